// Round 9
// baseline (22.303 us; speedup 1.0000x reference)
//
#include <hip/hip_runtime.h>
#include <math.h>

typedef __attribute__((ext_vector_type(8))) _Float16 f16x8;
typedef __attribute__((ext_vector_type(4))) float f32x4;

#define TSTEPS 23
#define ROWS 128

// ws byte offsets
#define WSB_B1 0        // [64 n][168 k] f16 combined table *256 (21504 B)
#define WSB_W2 21504    // [64 n][72 k] f16 rw2 transposed (9216 B)
#define WSB_U  30720    // [64 c][32 j] f32 ctx gate proj (8192 B)
#define WSB_V  38912    // [64 s][32 j] f32 mem gate proj (8192 B)
#define WSB_Z  47104    // [64][64] f32 RAW gate logit LUT (16384 B)

// ---- stage 1: u/v/B1/W2 tables (R6-proven pre_lite, B1 reg-cached) ----
__global__ __launch_bounds__(256) void pre_lite(
    const float* __restrict__ embed, const float* __restrict__ gw1,
    const float* __restrict__ rw1, const float* __restrict__ rb1,
    const float* __restrict__ rw2, char* __restrict__ wsc)
{
    __shared__ float sEmb[66 * 64];
    __shared__ float sW[128 * 64];
    __shared__ float sRb1[64];

    const int tid = threadIdx.x;
    const int blk = blockIdx.x;

    if (blk < 16) {
        // ---- u/v gate projections: 4096 outputs, 1/thread ----
        {
            const float4* es = (const float4*)embed;
            float4* ed = (float4*)sEmb;
            for (int i = tid; i < 1056; i += 256) ed[i] = es[i];
            const float4* gs = (const float4*)gw1;       // [128][32]
            float4* gd = (float4*)sW;
            for (int i = tid; i < 1024; i += 256) gd[i] = gs[i];
        }
        __syncthreads();
        const int e = blk * 256 + tid;                   // 0..4095
        const int row = (e >> 5) & 63, j = e & 31;
        const int ofs = (e < 2048) ? 0 : 64;
        float acc = 0.f;
        const float* er = sEmb + row * 64;
        #pragma unroll
        for (int k = 0; k < 64; ++k)
            acc = fmaf(er[k], sW[(ofs + k) * 32 + j], acc);
        float* dst = (float*)(wsc + ((e < 2048) ? WSB_U : WSB_V));
        dst[e & 2047] = acc;
    } else if (blk < 49) {
        // ---- B1 combined table: 8320 outputs, 1/thread, er reg-cached ----
        {
            const float4* es = (const float4*)embed;
            float4* ed = (float4*)sEmb;
            for (int i = tid; i < 1056; i += 256) ed[i] = es[i];
            const float4* rs = (const float4*)rw1;       // [128][64]
            float4* rd = (float4*)sW;
            for (int i = tid; i < 2048; i += 256) rd[i] = rs[i];
            if (tid < 64) sRb1[tid] = rb1[tid];
        }
        __syncthreads();
        const int e = (blk - 16) * 256 + tid;
        if (e < 8320) {
            const int n = e & 63, k = e >> 6;            // k < 130
            const int trow = (k < 64) ? k : (k - 64);
            const int ofs = (k < 64) ? 64 : 0;
            float4 er[16];
            const float4* erp = (const float4*)(sEmb + trow * 64);
            #pragma unroll
            for (int q = 0; q < 16; ++q) er[q] = erp[q];
            float acc = (k < 64) ? 0.f : sRb1[n];
            #pragma unroll
            for (int m = 0; m < 64; ++m)
                acc = fmaf(((const float*)er)[m], sW[(ofs + m) * 64 + n], acc);
            acc *= (k < 64) ? (0.125f * 256.f) : 256.f;
            ((_Float16*)(wsc + WSB_B1))[n * 168 + k] = (_Float16)acc;
        }
    } else {
        // ---- W2 transpose + B1 k-pads ----
        _Float16* w2t = (_Float16*)(wsc + WSB_W2);
        for (int e = tid; e < 4096; e += 256) {
            const int n = e & 63, j = e >> 6;
            w2t[n * 72 + j] = (_Float16)rw2[j * 64 + n];
        }
        _Float16* b1 = (_Float16*)(wsc + WSB_B1);
        for (int e = tid; e < 2432; e += 256) {          // k in [130,168)
            const int n = e / 38, k = 130 + (e - n * 38);
            b1[n * 168 + k] = (_Float16)0.f;
        }
    }
}

// ---- stage 2: RAW-LOGIT Z table (f64 dot, NO exp/div; 4-way ILP) ----
__global__ __launch_bounds__(256) void pre_z2(
    const float* __restrict__ gb1, const float* __restrict__ gw2,
    const float* __restrict__ gb2, char* __restrict__ wsc)
{
    __shared__ float sU[64 * 33];
    __shared__ float sV[64 * 33];
    __shared__ float sG1[32];
    __shared__ float sG2[32];

    const int tid = threadIdx.x;
    const float* u = (const float*)(wsc + WSB_U);
    const float* v = (const float*)(wsc + WSB_V);
    for (int i = tid; i < 2048; i += 256) {
        sU[(i >> 5) * 33 + (i & 31)] = u[i];
        sV[(i >> 5) * 33 + (i & 31)] = v[i];
    }
    if (tid < 32) { sG1[tid] = gb1[tid]; sG2[tid] = gw2[tid]; }
    __syncthreads();

    const int idx = blockIdx.x * 256 + tid;              // 0..4095
    const int c = idx >> 6, s = idx & 63;

    // register-prefetch the two 32-wide rows (breaks per-iter LDS latency)
    float ur[32], vr[32];
    #pragma unroll
    for (int j = 0; j < 32; ++j) { ur[j] = sU[c * 33 + j]; vr[j] = sV[s * 33 + j]; }

    double p0 = 0.0, p1 = 0.0, p2 = 0.0, p3 = 0.0;
    #pragma unroll
    for (int j = 0; j < 32; j += 4) {
        const double a0 = (double)ur[j]     + (double)vr[j]     + (double)sG1[j];
        const double a1 = (double)ur[j + 1] + (double)vr[j + 1] + (double)sG1[j + 1];
        const double a2 = (double)ur[j + 2] + (double)vr[j + 2] + (double)sG1[j + 2];
        const double a3 = (double)ur[j + 3] + (double)vr[j + 3] + (double)sG1[j + 3];
        if (a0 > 0.0) p0 += a0 * (double)sG2[j];
        if (a1 > 0.0) p1 += a1 * (double)sG2[j + 1];
        if (a2 > 0.0) p2 += a2 * (double)sG2[j + 2];
        if (a3 > 0.0) p3 += a3 * (double)sG2[j + 3];
    }
    const double z = (double)gb2[0] + ((p0 + p1) + (p2 + p3));
    ((float*)(wsc + WSB_Z))[idx] = (float)z;             // raw logit: monotone == sigmoid
}

// ---- A-window builders (unchanged) ----
__device__ __forceinline__ f16x8 build_slot_win(const unsigned* s, const unsigned* hb, int ko)
{
    unsigned w0 = 0, w1 = 0, w2 = 0, w3 = 0;
    #pragma unroll
    for (int i = 0; i < 8; ++i) {
        const unsigned d = s[i] - (unsigned)ko;
        const unsigned val = (d < 8u) ? (hb[i] << ((d & 1u) * 16)) : 0u;
        const unsigned q = d >> 1;
        w0 |= (q == 0u) ? val : 0u;
        w1 |= (q == 1u) ? val : 0u;
        w2 |= (q == 2u) ? val : 0u;
        w3 |= (q == 3u) ? val : 0u;
    }
    union { unsigned u[4]; f16x8 v; } r;
    r.u[0] = w0; r.u[1] = w1; r.u[2] = w2; r.u[3] = w3;
    return r.v;
}

__device__ __forceinline__ f16x8 build_q_win(int kq, int ko)
{
    const unsigned d = (unsigned)(kq - ko);
    const unsigned val = (d < 8u) ? (0x3C00u << ((d & 1u) * 16)) : 0u;
    const unsigned q = d >> 1;
    union { unsigned u[4]; f16x8 v; } r;
    r.u[0] = (q == 0u) ? val : 0u;
    r.u[1] = (q == 1u) ? val : 0u;
    r.u[2] = (q == 2u) ? val : 0u;
    r.u[3] = (q == 3u) ? val : 0u;
    return r.v;
}

// LDS byte offsets (67840 B arena) — sOut f32[128][68] overlays [0, 34816)
#define L_Z    0
#define L_B1   16384
#define L_W2   37888
#define L_H    47104
#define L_ROW  65536
#define L_RB2  67584

__global__ __launch_bounds__(512, 4) void sm_main(
    const int* __restrict__ seqs, const int* __restrict__ qtok,
    const float* __restrict__ rb2, const char* __restrict__ wsc,
    float* __restrict__ out)
{
    __shared__ __align__(16) char smem[67840];
    float*    sZ   = (float*)(smem + L_Z);
    _Float16* sB1  = (_Float16*)(smem + L_B1);
    _Float16* sW2  = (_Float16*)(smem + L_W2);
    _Float16* sH   = (_Float16*)(smem + L_H);
    uint4*    sRow = (uint4*)(smem + L_ROW);
    float*    sRb2 = (float*)(smem + L_RB2);

    const int tid = threadIdx.x;
    const int base = blockIdx.x * ROWS;

    // ---- early token prefetch ----
    unsigned pk[6];
    int qt = 0;
    if (tid < ROWS) {
        const int4* sq = (const int4*)(seqs + (size_t)(base + tid) * 24);
        #pragma unroll
        for (int i = 0; i < 6; ++i) {
            const int4 w4 = sq[i];
            pk[i] = (unsigned)w4.x | ((unsigned)w4.y << 8) |
                    ((unsigned)w4.z << 16) | ((unsigned)w4.w << 24);
        }
        qt = qtok[base + tid];
    }

    // ---- phase 0: stage Z (raw-logit LUT) + rb2 only ----
    {
        const float4* zsrc = (const float4*)(wsc + WSB_Z);
        float4* zdst = (float4*)sZ;
        #pragma unroll
        for (int i = 0; i < 2; ++i) zdst[tid + i * 512] = zsrc[tid + i * 512];
        if (tid < 64) sRb2[tid] = rb2[tid];
    }
    __syncthreads();

    // ---- phase 1: scan (tid<128) || stage B1/W2 (tid>=128) ----
    if (tid < ROWS) {
        unsigned lo = pk[0], hi = pk[1];
        #pragma unroll
        for (int t = 8; t < TSTEPS; ++t) {
            const int c = (int)((pk[t >> 2] >> ((t & 3) * 8)) & 255u);
            const float* zr = sZ + c * 64;
            float b = zr[lo & 63]; int am = 0; float z;
            z = zr[(lo >> 8) & 63];  if (z > b) { b = z; am = 1; }
            z = zr[(lo >> 16) & 63]; if (z > b) { b = z; am = 2; }
            z = zr[lo >> 24];        if (z > b) { b = z; am = 3; }
            z = zr[hi & 63];         if (z > b) { b = z; am = 4; }
            z = zr[(hi >> 8) & 63];  if (z > b) { b = z; am = 5; }
            z = zr[(hi >> 16) & 63]; if (z > b) { b = z; am = 6; }
            z = zr[hi >> 24];        if (z > b) { b = z; am = 7; }
            const unsigned cb = (unsigned)c;
            if (am < 4) { const int sh = am * 8; lo = (lo & ~(255u << sh)) | (cb << sh); }
            else        { const int sh = am * 8 - 32; hi = (hi & ~(255u << sh)) | (cb << sh); }
        }
        int t_[8] = { (int)(lo & 63), (int)((lo >> 8) & 63), (int)((lo >> 16) & 63), (int)(lo >> 24),
                      (int)(hi & 63), (int)((hi >> 8) & 63), (int)((hi >> 16) & 63), (int)(hi >> 24) };
        int tot[8] = {1, 1, 1, 1, 1, 1, 1, 1};
        #pragma unroll
        for (int i = 0; i < 8; ++i)
            #pragma unroll
            for (int j = i + 1; j < 8; ++j) {
                const int eq = (t_[i] == t_[j]);
                tot[i] += eq; tot[j] += eq;
            }
        unsigned tp = 0;
        #pragma unroll
        for (int i = 0; i < 8; ++i) tp |= (unsigned)tot[i] << (4 * i);
        sRow[tid] = make_uint4(lo & 0x3F3F3F3Fu, hi & 0x3F3F3F3Fu, tp, (unsigned)qt);
    } else {
        const int t2 = tid - 128;   // 0..383
        const float4* b1s = (const float4*)(wsc + WSB_B1);
        float4* b1d = (float4*)sB1;
        for (int i = t2; i < 1344; i += 384) b1d[i] = b1s[i];
        const float4* w2s = (const float4*)(wsc + WSB_W2);
        float4* w2d = (float4*)sW2;
        for (int i = t2; i < 576; i += 384) w2d[i] = w2s[i];
    }
    __syncthreads();

    // ---- phase 2: MFMA-1  h = A @ B1 (K=160), A built in registers ----
    const int lane = tid & 63;
    const int w = tid >> 6;
    const int c16 = lane & 15, g = lane >> 4;
    const int arow = w * 16 + c16;

    unsigned sl[8], hb[8];
    int kq;
    {
        const uint4 ri = sRow[arow];
        sl[0] = ri.x & 63u; sl[1] = (ri.x >> 8) & 63u;
        sl[2] = (ri.x >> 16) & 63u; sl[3] = ri.x >> 24;
        sl[4] = ri.y & 63u; sl[5] = (ri.y >> 8) & 63u;
        sl[6] = (ri.y >> 16) & 63u; sl[7] = ri.y >> 24;
        #pragma unroll
        for (int i = 0; i < 8; ++i) {
            const unsigned tot = (ri.z >> (4 * i)) & 15u;
            union { _Float16 h; unsigned short b; } cv;
            cv.h = (_Float16)(float)tot;
            hb[i] = (unsigned)cv.b;
        }
        kq = 64 + (int)ri.w;
    }

    f32x4 a0 = {0.f, 0.f, 0.f, 0.f}, a1 = a0, a2 = a0, a3 = a0;
    #pragma unroll
    for (int ks = 0; ks < 5; ++ks) {
        const int ko = ks * 32 + g * 8;
        const f16x8 af = (ks < 2) ? build_slot_win(sl, hb, ko) : build_q_win(kq, ko);
        const f16x8 b0 = *(const f16x8*)&sB1[(c16) * 168 + ko];
        const f16x8 b1 = *(const f16x8*)&sB1[(16 + c16) * 168 + ko];
        const f16x8 b2 = *(const f16x8*)&sB1[(32 + c16) * 168 + ko];
        const f16x8 b3 = *(const f16x8*)&sB1[(48 + c16) * 168 + ko];
        a0 = __builtin_amdgcn_mfma_f32_16x16x32_f16(af, b0, a0, 0, 0, 0);
        a1 = __builtin_amdgcn_mfma_f32_16x16x32_f16(af, b1, a1, 0, 0, 0);
        a2 = __builtin_amdgcn_mfma_f32_16x16x32_f16(af, b2, a2, 0, 0, 0);
        a3 = __builtin_amdgcn_mfma_f32_16x16x32_f16(af, b3, a3, 0, 0, 0);
    }
    {
        const int rbase = w * 16 + g * 4;
        #pragma unroll
        for (int j = 0; j < 4; ++j) {
            _Float16* hr = sH + (rbase + j) * 72;
            const float v0 = a0[j], v1 = a1[j], v2 = a2[j], v3 = a3[j];
            hr[c16]      = (_Float16)(v0 > 0.f ? v0 : 0.f);
            hr[16 + c16] = (_Float16)(v1 > 0.f ? v1 : 0.f);
            hr[32 + c16] = (_Float16)(v2 > 0.f ? v2 : 0.f);
            hr[48 + c16] = (_Float16)(v3 > 0.f ? v3 : 0.f);
        }
    }
    __syncthreads();

    // ---- phase 3: MFMA-2  logits = relu(h) @ W2t (K=64) ----
    f32x4 d0 = {0.f, 0.f, 0.f, 0.f}, d1 = d0, d2 = d0, d3 = d0;
    #pragma unroll
    for (int ks = 0; ks < 2; ++ks) {
        const int ko = ks * 32 + g * 8;
        const f16x8 af = *(const f16x8*)&sH[arow * 72 + ko];
        const f16x8 b0 = *(const f16x8*)&sW2[(c16) * 72 + ko];
        const f16x8 b1 = *(const f16x8*)&sW2[(16 + c16) * 72 + ko];
        const f16x8 b2 = *(const f16x8*)&sW2[(32 + c16) * 72 + ko];
        const f16x8 b3 = *(const f16x8*)&sW2[(48 + c16) * 72 + ko];
        d0 = __builtin_amdgcn_mfma_f32_16x16x32_f16(af, b0, d0, 0, 0, 0);
        d1 = __builtin_amdgcn_mfma_f32_16x16x32_f16(af, b1, d1, 0, 0, 0);
        d2 = __builtin_amdgcn_mfma_f32_16x16x32_f16(af, b2, d2, 0, 0, 0);
        d3 = __builtin_amdgcn_mfma_f32_16x16x32_f16(af, b3, d3, 0, 0, 0);
    }
    float* sOut = (float*)(void*)smem;      // overlays dead sZ/sB1
    {
        const int rbase = w * 16 + g * 4;
        #pragma unroll
        for (int j = 0; j < 4; ++j) {
            float* orow = sOut + (rbase + j) * 68;
            orow[c16]      = d0[j] * (1.f / 256.f) + sRb2[c16];
            orow[16 + c16] = d1[j] * (1.f / 256.f) + sRb2[16 + c16];
            orow[32 + c16] = d2[j] * (1.f / 256.f) + sRb2[32 + c16];
            orow[48 + c16] = d3[j] * (1.f / 256.f) + sRb2[48 + c16];
        }
    }
    __syncthreads();

    // ---- phase 4: coalesced store ----
    #pragma unroll
    for (int r2 = 0; r2 < 4; ++r2) {
        const int idx = r2 * 512 + tid;
        const int row = idx >> 4, c4 = idx & 15;
        *(float4*)(out + (size_t)(base + row) * 64 + c4 * 4) =
            *(const float4*)&sOut[row * 68 + c4 * 4];
    }
}

extern "C" void kernel_launch(void* const* d_in, const int* in_sizes, int n_in,
                              void* d_out, int out_size, void* d_ws, size_t ws_size,
                              hipStream_t stream)
{
    const int* seqs    = (const int*)d_in[0];
    const int* qtok    = (const int*)d_in[1];
    const float* embed = (const float*)d_in[2];
    const float* gw1   = (const float*)d_in[3];
    const float* gb1   = (const float*)d_in[4];
    const float* gw2   = (const float*)d_in[5];
    const float* gb2   = (const float*)d_in[6];
    const float* rw1   = (const float*)d_in[7];
    const float* rb1   = (const float*)d_in[8];
    const float* rw2   = (const float*)d_in[9];
    const float* rb2   = (const float*)d_in[10];
    char* wsc  = (char*)d_ws;
    float* out = (float*)d_out;
    const int B = in_sizes[1];

    pre_lite<<<50, 256, 0, stream>>>(embed, gw1, rw1, rb1, rw2, wsc);
    pre_z2<<<16, 256, 0, stream>>>(gb1, gw2, gb2, wsc);
    sm_main<<<B / ROWS, 512, 0, stream>>>(seqs, qtok, rb2, wsc, out);
}

// Round 10
// 19.544 us; speedup vs baseline: 1.1412x; 1.1412x over previous
//
#include <hip/hip_runtime.h>
#include <math.h>

typedef __attribute__((ext_vector_type(8))) _Float16 f16x8;
typedef __attribute__((ext_vector_type(4))) float f32x4;

#define TSTEPS 23
#define ROWS 128

// ws byte offsets
#define WSB_B1 0        // [64 n][168 k] f16 combined table *256 (21504 B)
#define WSB_W2 21504    // [64 n][72 k] f16 rw2 transposed (9216 B)
#define WSB_Z  30720    // [64][64] f32 RAW gate logit LUT (16384 B)

// ---- single precompute kernel: Z (blocks 0-15, self-contained), B1, W2 ----
__global__ __launch_bounds__(256) void pre_all(
    const float* __restrict__ embed, const float* __restrict__ gw1,
    const float* __restrict__ gb1, const float* __restrict__ gw2,
    const float* __restrict__ gb2, const float* __restrict__ rw1,
    const float* __restrict__ rb1, const float* __restrict__ rw2,
    char* __restrict__ wsc)
{
    __shared__ float sEmb[66 * 64];   // 16896 B
    __shared__ float sW[128 * 64];    // 32768 B (gw1 uses half)
    __shared__ float sV[64 * 33];     // 8448 B
    __shared__ float sU[4 * 32];
    __shared__ float sG[65];          // gb1[0:32], gw2[32:64], gb2[64]
    __shared__ float sRb1[64];

    const int tid = threadIdx.x;
    const int blk = blockIdx.x;

    if (blk < 16) {
        // ---- Z rows c in [blk*4, blk*4+4), fully in-block ----
        {
            const float4* es = (const float4*)embed;
            float4* ed = (float4*)sEmb;
            for (int i = tid; i < 1024; i += 256) ed[i] = es[i];
            const float4* gs = (const float4*)gw1;       // [128][32] = 1024 f4
            float4* gd = (float4*)sW;
            for (int i = tid; i < 1024; i += 256) gd[i] = gs[i];
            if (tid < 32) { sG[tid] = gb1[tid]; sG[32 + tid] = gw2[tid]; }
            if (tid == 64) sG[64] = gb2[0];
        }
        __syncthreads();
        // v: s = tid>>2 (er reg-cached), 8 consecutive j — bitwise == R8 chain
        {
            const int s = tid >> 2, j0 = (tid & 3) * 8;
            float4 er[16];
            const float4* erp = (const float4*)(sEmb + s * 64);
            #pragma unroll
            for (int q = 0; q < 16; ++q) er[q] = erp[q];
            float acc[8] = {0.f, 0.f, 0.f, 0.f, 0.f, 0.f, 0.f, 0.f};
            #pragma unroll
            for (int k = 0; k < 64; ++k) {
                const float ek = ((const float*)er)[k];
                const float4 w0 = *(const float4*)&sW[(64 + k) * 32 + j0];
                const float4 w1 = *(const float4*)&sW[(64 + k) * 32 + j0 + 4];
                acc[0] = fmaf(ek, w0.x, acc[0]); acc[1] = fmaf(ek, w0.y, acc[1]);
                acc[2] = fmaf(ek, w0.z, acc[2]); acc[3] = fmaf(ek, w0.w, acc[3]);
                acc[4] = fmaf(ek, w1.x, acc[4]); acc[5] = fmaf(ek, w1.y, acc[5]);
                acc[6] = fmaf(ek, w1.z, acc[6]); acc[7] = fmaf(ek, w1.w, acc[7]);
            }
            #pragma unroll
            for (int jj = 0; jj < 8; ++jj) sV[s * 33 + jj + j0] = acc[jj];
        }
        if (tid < 128) {                                 // u: 4 c-rows × 32 j
            const int cc = tid >> 5, j = tid & 31;
            const int c = blk * 4 + cc;
            float acc = 0.f;
            const float* er = sEmb + c * 64;
            #pragma unroll
            for (int k = 0; k < 64; ++k)
                acc = fmaf(er[k], sW[k * 32 + j], acc);
            sU[cc * 32 + j] = acc;
        }
        __syncthreads();
        // raw-logit f64 combine (R9-proven: 4-way ILP, no exp/div)
        {
            const int cc = tid >> 6, s = tid & 63;
            const int c = blk * 4 + cc;
            float ur[32], vr[32];
            #pragma unroll
            for (int j = 0; j < 32; ++j) { ur[j] = sU[cc * 32 + j]; vr[j] = sV[s * 33 + j]; }
            double p0 = 0.0, p1 = 0.0, p2 = 0.0, p3 = 0.0;
            #pragma unroll
            for (int j = 0; j < 32; j += 4) {
                const double a0 = (double)ur[j]     + (double)vr[j]     + (double)sG[j];
                const double a1 = (double)ur[j + 1] + (double)vr[j + 1] + (double)sG[j + 1];
                const double a2 = (double)ur[j + 2] + (double)vr[j + 2] + (double)sG[j + 2];
                const double a3 = (double)ur[j + 3] + (double)vr[j + 3] + (double)sG[j + 3];
                if (a0 > 0.0) p0 += a0 * (double)sG[32 + j];
                if (a1 > 0.0) p1 += a1 * (double)sG[32 + j + 1];
                if (a2 > 0.0) p2 += a2 * (double)sG[32 + j + 2];
                if (a3 > 0.0) p3 += a3 * (double)sG[32 + j + 3];
            }
            const double z = (double)sG[64] + ((p0 + p1) + (p2 + p3));
            ((float*)(wsc + WSB_Z))[c * 64 + s] = (float)z;
        }
    } else if (blk < 49) {
        // ---- B1 combined table: 8320 outputs, 1/thread, er reg-cached ----
        {
            const float4* es = (const float4*)embed;
            float4* ed = (float4*)sEmb;
            for (int i = tid; i < 1056; i += 256) ed[i] = es[i];
            const float4* rs = (const float4*)rw1;       // [128][64]
            float4* rd = (float4*)sW;
            for (int i = tid; i < 2048; i += 256) rd[i] = rs[i];
            if (tid < 64) sRb1[tid] = rb1[tid];
        }
        __syncthreads();
        const int e = (blk - 16) * 256 + tid;
        if (e < 8320) {
            const int n = e & 63, k = e >> 6;            // k < 130
            const int trow = (k < 64) ? k : (k - 64);
            const int ofs = (k < 64) ? 64 : 0;
            float4 er[16];
            const float4* erp = (const float4*)(sEmb + trow * 64);
            #pragma unroll
            for (int q = 0; q < 16; ++q) er[q] = erp[q];
            float acc = (k < 64) ? 0.f : sRb1[n];
            #pragma unroll
            for (int m = 0; m < 64; ++m)
                acc = fmaf(((const float*)er)[m], sW[(ofs + m) * 64 + n], acc);
            acc *= (k < 64) ? (0.125f * 256.f) : 256.f;
            ((_Float16*)(wsc + WSB_B1))[n * 168 + k] = (_Float16)acc;
        }
    } else {
        // ---- W2 transpose + B1 k-pads ----
        _Float16* w2t = (_Float16*)(wsc + WSB_W2);
        for (int e = tid; e < 4096; e += 256) {
            const int n = e & 63, j = e >> 6;
            w2t[n * 72 + j] = (_Float16)rw2[j * 64 + n];
        }
        _Float16* b1 = (_Float16*)(wsc + WSB_B1);
        for (int e = tid; e < 2432; e += 256) {          // k in [130,168)
            const int n = e / 38, k = 130 + (e - n * 38);
            b1[n * 168 + k] = (_Float16)0.f;
        }
    }
}

// ---- A-window builders (unchanged) ----
__device__ __forceinline__ f16x8 build_slot_win(const unsigned* s, const unsigned* hb, int ko)
{
    unsigned w0 = 0, w1 = 0, w2 = 0, w3 = 0;
    #pragma unroll
    for (int i = 0; i < 8; ++i) {
        const unsigned d = s[i] - (unsigned)ko;
        const unsigned val = (d < 8u) ? (hb[i] << ((d & 1u) * 16)) : 0u;
        const unsigned q = d >> 1;
        w0 |= (q == 0u) ? val : 0u;
        w1 |= (q == 1u) ? val : 0u;
        w2 |= (q == 2u) ? val : 0u;
        w3 |= (q == 3u) ? val : 0u;
    }
    union { unsigned u[4]; f16x8 v; } r;
    r.u[0] = w0; r.u[1] = w1; r.u[2] = w2; r.u[3] = w3;
    return r.v;
}

__device__ __forceinline__ f16x8 build_q_win(int kq, int ko)
{
    const unsigned d = (unsigned)(kq - ko);
    const unsigned val = (d < 8u) ? (0x3C00u << ((d & 1u) * 16)) : 0u;
    const unsigned q = d >> 1;
    union { unsigned u[4]; f16x8 v; } r;
    r.u[0] = (q == 0u) ? val : 0u;
    r.u[1] = (q == 1u) ? val : 0u;
    r.u[2] = (q == 2u) ? val : 0u;
    r.u[3] = (q == 3u) ? val : 0u;
    return r.v;
}

// LDS byte offsets (67840 B arena) — sOut f32[128][68] overlays [0, 34816)
#define L_Z    0
#define L_B1   16384
#define L_W2   37888
#define L_H    47104
#define L_ROW  65536
#define L_RB2  67584

__global__ __launch_bounds__(512, 4) void sm_main(
    const int* __restrict__ seqs, const int* __restrict__ qtok,
    const float* __restrict__ rb2, const char* __restrict__ wsc,
    float* __restrict__ out)
{
    __shared__ __align__(16) char smem[67840];
    float*    sZ   = (float*)(smem + L_Z);
    _Float16* sB1  = (_Float16*)(smem + L_B1);
    _Float16* sW2  = (_Float16*)(smem + L_W2);
    _Float16* sH   = (_Float16*)(smem + L_H);
    uint4*    sRow = (uint4*)(smem + L_ROW);
    float*    sRb2 = (float*)(smem + L_RB2);

    const int tid = threadIdx.x;
    const int base = blockIdx.x * ROWS;

    unsigned pk[6];
    int qt = 0;
    if (tid < ROWS) {
        const int4* sq = (const int4*)(seqs + (size_t)(base + tid) * 24);
        #pragma unroll
        for (int i = 0; i < 6; ++i) {
            const int4 w4 = sq[i];
            pk[i] = (unsigned)w4.x | ((unsigned)w4.y << 8) |
                    ((unsigned)w4.z << 16) | ((unsigned)w4.w << 24);
        }
        qt = qtok[base + tid];
    }

    {
        const float4* zsrc = (const float4*)(wsc + WSB_Z);
        float4* zdst = (float4*)sZ;
        #pragma unroll
        for (int i = 0; i < 2; ++i) zdst[tid + i * 512] = zsrc[tid + i * 512];
        if (tid < 64) sRb2[tid] = rb2[tid];
    }
    __syncthreads();

    if (tid < ROWS) {
        unsigned lo = pk[0], hi = pk[1];
        #pragma unroll
        for (int t = 8; t < TSTEPS; ++t) {
            const int c = (int)((pk[t >> 2] >> ((t & 3) * 8)) & 255u);
            const float* zr = sZ + c * 64;
            float b = zr[lo & 63]; int am = 0; float z;
            z = zr[(lo >> 8) & 63];  if (z > b) { b = z; am = 1; }
            z = zr[(lo >> 16) & 63]; if (z > b) { b = z; am = 2; }
            z = zr[lo >> 24];        if (z > b) { b = z; am = 3; }
            z = zr[hi & 63];         if (z > b) { b = z; am = 4; }
            z = zr[(hi >> 8) & 63];  if (z > b) { b = z; am = 5; }
            z = zr[(hi >> 16) & 63]; if (z > b) { b = z; am = 6; }
            z = zr[hi >> 24];        if (z > b) { b = z; am = 7; }
            const unsigned cb = (unsigned)c;
            if (am < 4) { const int sh = am * 8; lo = (lo & ~(255u << sh)) | (cb << sh); }
            else        { const int sh = am * 8 - 32; hi = (hi & ~(255u << sh)) | (cb << sh); }
        }
        int t_[8] = { (int)(lo & 63), (int)((lo >> 8) & 63), (int)((lo >> 16) & 63), (int)(lo >> 24),
                      (int)(hi & 63), (int)((hi >> 8) & 63), (int)((hi >> 16) & 63), (int)(hi >> 24) };
        int tot[8] = {1, 1, 1, 1, 1, 1, 1, 1};
        #pragma unroll
        for (int i = 0; i < 8; ++i)
            #pragma unroll
            for (int j = i + 1; j < 8; ++j) {
                const int eq = (t_[i] == t_[j]);
                tot[i] += eq; tot[j] += eq;
            }
        unsigned tp = 0;
        #pragma unroll
        for (int i = 0; i < 8; ++i) tp |= (unsigned)tot[i] << (4 * i);
        sRow[tid] = make_uint4(lo & 0x3F3F3F3Fu, hi & 0x3F3F3F3Fu, tp, (unsigned)qt);
    } else {
        const int t2 = tid - 128;
        const float4* b1s = (const float4*)(wsc + WSB_B1);
        float4* b1d = (float4*)sB1;
        for (int i = t2; i < 1344; i += 384) b1d[i] = b1s[i];
        const float4* w2s = (const float4*)(wsc + WSB_W2);
        float4* w2d = (float4*)sW2;
        for (int i = t2; i < 576; i += 384) w2d[i] = w2s[i];
    }
    __syncthreads();

    const int lane = tid & 63;
    const int w = tid >> 6;
    const int c16 = lane & 15, g = lane >> 4;
    const int arow = w * 16 + c16;

    unsigned sl[8], hb[8];
    int kq;
    {
        const uint4 ri = sRow[arow];
        sl[0] = ri.x & 63u; sl[1] = (ri.x >> 8) & 63u;
        sl[2] = (ri.x >> 16) & 63u; sl[3] = ri.x >> 24;
        sl[4] = ri.y & 63u; sl[5] = (ri.y >> 8) & 63u;
        sl[6] = (ri.y >> 16) & 63u; sl[7] = ri.y >> 24;
        #pragma unroll
        for (int i = 0; i < 8; ++i) {
            const unsigned tot = (ri.z >> (4 * i)) & 15u;
            union { _Float16 h; unsigned short b; } cv;
            cv.h = (_Float16)(float)tot;
            hb[i] = (unsigned)cv.b;
        }
        kq = 64 + (int)ri.w;
    }

    f32x4 a0 = {0.f, 0.f, 0.f, 0.f}, a1 = a0, a2 = a0, a3 = a0;
    #pragma unroll
    for (int ks = 0; ks < 5; ++ks) {
        const int ko = ks * 32 + g * 8;
        const f16x8 af = (ks < 2) ? build_slot_win(sl, hb, ko) : build_q_win(kq, ko);
        const f16x8 b0 = *(const f16x8*)&sB1[(c16) * 168 + ko];
        const f16x8 b1 = *(const f16x8*)&sB1[(16 + c16) * 168 + ko];
        const f16x8 b2 = *(const f16x8*)&sB1[(32 + c16) * 168 + ko];
        const f16x8 b3 = *(const f16x8*)&sB1[(48 + c16) * 168 + ko];
        a0 = __builtin_amdgcn_mfma_f32_16x16x32_f16(af, b0, a0, 0, 0, 0);
        a1 = __builtin_amdgcn_mfma_f32_16x16x32_f16(af, b1, a1, 0, 0, 0);
        a2 = __builtin_amdgcn_mfma_f32_16x16x32_f16(af, b2, a2, 0, 0, 0);
        a3 = __builtin_amdgcn_mfma_f32_16x16x32_f16(af, b3, a3, 0, 0, 0);
    }
    {
        const int rbase = w * 16 + g * 4;
        #pragma unroll
        for (int j = 0; j < 4; ++j) {
            _Float16* hr = sH + (rbase + j) * 72;
            const float v0 = a0[j], v1 = a1[j], v2 = a2[j], v3 = a3[j];
            hr[c16]      = (_Float16)(v0 > 0.f ? v0 : 0.f);
            hr[16 + c16] = (_Float16)(v1 > 0.f ? v1 : 0.f);
            hr[32 + c16] = (_Float16)(v2 > 0.f ? v2 : 0.f);
            hr[48 + c16] = (_Float16)(v3 > 0.f ? v3 : 0.f);
        }
    }
    __syncthreads();

    f32x4 d0 = {0.f, 0.f, 0.f, 0.f}, d1 = d0, d2 = d0, d3 = d0;
    #pragma unroll
    for (int ks = 0; ks < 2; ++ks) {
        const int ko = ks * 32 + g * 8;
        const f16x8 af = *(const f16x8*)&sH[arow * 72 + ko];
        const f16x8 b0 = *(const f16x8*)&sW2[(c16) * 72 + ko];
        const f16x8 b1 = *(const f16x8*)&sW2[(16 + c16) * 72 + ko];
        const f16x8 b2 = *(const f16x8*)&sW2[(32 + c16) * 72 + ko];
        const f16x8 b3 = *(const f16x8*)&sW2[(48 + c16) * 72 + ko];
        d0 = __builtin_amdgcn_mfma_f32_16x16x32_f16(af, b0, d0, 0, 0, 0);
        d1 = __builtin_amdgcn_mfma_f32_16x16x32_f16(af, b1, d1, 0, 0, 0);
        d2 = __builtin_amdgcn_mfma_f32_16x16x32_f16(af, b2, d2, 0, 0, 0);
        d3 = __builtin_amdgcn_mfma_f32_16x16x32_f16(af, b3, d3, 0, 0, 0);
    }
    float* sOut = (float*)(void*)smem;
    {
        const int rbase = w * 16 + g * 4;
        #pragma unroll
        for (int j = 0; j < 4; ++j) {
            float* orow = sOut + (rbase + j) * 68;
            orow[c16]      = d0[j] * (1.f / 256.f) + sRb2[c16];
            orow[16 + c16] = d1[j] * (1.f / 256.f) + sRb2[16 + c16];
            orow[32 + c16] = d2[j] * (1.f / 256.f) + sRb2[32 + c16];
            orow[48 + c16] = d3[j] * (1.f / 256.f) + sRb2[48 + c16];
        }
    }
    __syncthreads();

    #pragma unroll
    for (int r2 = 0; r2 < 4; ++r2) {
        const int idx = r2 * 512 + tid;
        const int row = idx >> 4, c4 = idx & 15;
        *(float4*)(out + (size_t)(base + row) * 64 + c4 * 4) =
            *(const float4*)&sOut[row * 68 + c4 * 4];
    }
}

extern "C" void kernel_launch(void* const* d_in, const int* in_sizes, int n_in,
                              void* d_out, int out_size, void* d_ws, size_t ws_size,
                              hipStream_t stream)
{
    const int* seqs    = (const int*)d_in[0];
    const int* qtok    = (const int*)d_in[1];
    const float* embed = (const float*)d_in[2];
    const float* gw1   = (const float*)d_in[3];
    const float* gb1   = (const float*)d_in[4];
    const float* gw2   = (const float*)d_in[5];
    const float* gb2   = (const float*)d_in[6];
    const float* rw1   = (const float*)d_in[7];
    const float* rb1   = (const float*)d_in[8];
    const float* rw2   = (const float*)d_in[9];
    const float* rb2   = (const float*)d_in[10];
    char* wsc  = (char*)d_ws;
    float* out = (float*)d_out;
    const int B = in_sizes[1];

    pre_all<<<50, 256, 0, stream>>>(embed, gw1, gb1, gw2, gb2, rw1, rb1, rw2, wsc);
    sm_main<<<B / ROWS, 512, 0, stream>>>(seqs, qtok, rb2, wsc, out);
}